// Round 4
// baseline (128.634 us; speedup 1.0000x reference)
//
#include <hip/hip_runtime.h>

// ---------------------------------------------------------------------------
// KAN conv layer: out[b,o,i,j] = sum_{c,p} silu(patch)*bw[o,c,p]
//                              + sum_{c,p,g} Bspline_g(patch)*sw[o,c,p,g]*sc[o,c,p]
// B=16 CIN=32 COUT=64 H=W=64 K=3 -> Ho=Wo=62, P=9, G+k=8 bases
// bf16 MFMA implicit GEMM, K = 2592 = 81 steps of 32 (72 spline + 9 silu).
// R4: LDS-staged K-periods. R1-R3 showed the kernel is bound by a shared
//     per-CU resource (4x TLP was neutral): every wave streamed 648 KB of
//     fragments through L1/L2 (643 MB aggregate). Now each block stages one
//     9-step period (36 KB weights + 16 KB features) into LDS once via
//     global_load_lds(16B) and fragment-reads from LDS. Global traffic drops
//     ~12x; fragments ride the 128 B/cyc LDS pipe. 2 waves/block = 2 rows,
//     496 blocks, 107 KB LDS -> 2 blocks/CU (mutual stage-drain hiding).
// ---------------------------------------------------------------------------

typedef short v8s __attribute__((ext_vector_type(8)));
typedef float v4f __attribute__((ext_vector_type(4)));

#define FSPL_OFF   0u
#define FSILU_OFF  33554688u          // 33554432 (Fspl) + 256 pad
#define WPACK_OFF  37749248u          // FSILU_OFF + 4194304 (Fsil) + 256 pad

__device__ __forceinline__ unsigned short f2bf(float f) {
  unsigned int u = __float_as_uint(f);
  u += 0x7fffu + ((u >> 16) & 1u);          // round-to-nearest-even
  return (unsigned short)(u >> 16);
}

// ---- kernel 1: spline bases per input element -> Fspl[b][c][y][x][g8] ------
__global__ __launch_bounds__(256) void k_spline(const float* __restrict__ x,
                                                unsigned char* __restrict__ ws) {
  int pix = blockIdx.x * 256 + threadIdx.x;      // 2,097,152 elements
  float v = x[pix];
  float bb[11];
#pragma unroll
  for (int i = 0; i < 11; ++i) {
    float t0 = -2.2f + 0.4f * i;
    bb[i] = (v >= t0 && v < t0 + 0.4f) ? 1.0f : 0.0f;
  }
#pragma unroll
  for (int j = 1; j <= 3; ++j) {
    float rj = 1.0f / (0.4f * j);
#pragma unroll
    for (int i = 0; i + j < 11; ++i) {
      float ti = -2.2f + 0.4f * i;
      float lf = (v - ti) * rj;
      float rt = ((ti + 0.4f * (j + 1)) - v) * rj;
      bb[i] = lf * bb[i] + rt * bb[i + 1];
    }
  }
  uint4 o;
  o.x = (unsigned)f2bf(bb[0]) | ((unsigned)f2bf(bb[1]) << 16);
  o.y = (unsigned)f2bf(bb[2]) | ((unsigned)f2bf(bb[3]) << 16);
  o.z = (unsigned)f2bf(bb[4]) | ((unsigned)f2bf(bb[5]) << 16);
  o.w = (unsigned)f2bf(bb[6]) | ((unsigned)f2bf(bb[7]) << 16);
  *(uint4*)(ws + FSPL_OFF + (size_t)pix * 16) = o;
}

// ---- kernel 2: silu, transposed -> Fsil[b][y][x][c32] ----------------------
__global__ __launch_bounds__(256) void k_silu(const float* __restrict__ x,
                                              unsigned char* __restrict__ ws) {
  int bid = blockIdx.x;                  // b*64 + y
  int b = bid >> 6, y = bid & 63;
  int t = threadIdx.x;
  int xx = t & 63, cg = t >> 6;
  unsigned short h[8];
#pragma unroll
  for (int k = 0; k < 8; ++k) {
    int c = cg * 8 + k;
    float v = x[(((size_t)(b * 32 + c) * 64 + y) * 64) + xx];
    float s = v / (1.0f + __expf(-v));
    h[k] = f2bf(s);
  }
  uint4 o;
  o.x = (unsigned)h[0] | ((unsigned)h[1] << 16);
  o.y = (unsigned)h[2] | ((unsigned)h[3] << 16);
  o.z = (unsigned)h[4] | ((unsigned)h[5] << 16);
  o.w = (unsigned)h[6] | ((unsigned)h[7] << 16);
  *(uint4*)(ws + FSILU_OFF + (size_t)(b * 4096 + y * 64 + xx) * 64 + cg * 16) = o;
}

// ---- kernel 3: pack weights in MFMA A-fragment order -----------------------
__global__ __launch_bounds__(256) void k_wpack(const float* __restrict__ bw,
                                               const float* __restrict__ sw,
                                               const float* __restrict__ sc,
                                               unsigned char* __restrict__ ws) {
  int tid = blockIdx.x * 256 + threadIdx.x;
  if (tid >= 165888) return;             // 81*4*64*8
  int e = tid & 7, lane = (tid >> 3) & 63, ot = (tid >> 9) & 3, s = tid >> 11;
  int k = s * 32 + ((lane >> 4) << 3) + e;
  int o = (ot << 4) + (lane & 15);
  float val;
  if (k < 2304) {
    int chunk = k / 24, u = k - chunk * 24;
    int dj = u >> 3, g = u & 7;
    int c = chunk / 3, di = chunk - c * 3;
    int p = di * 3 + dj;
    val = sw[((size_t)(o * 32 + c) * 9 + p) * 8 + g] * sc[(size_t)(o * 32 + c) * 9 + p];
  } else {
    int k2 = k - 2304;
    int tp = k2 >> 5, cc = k2 & 31;
    val = bw[(size_t)(o * 32 + cc) * 9 + tp];
  }
  *(unsigned short*)(ws + WPACK_OFF + (size_t)tid * 2) = f2bf(val);
}

// ---- async 16B global -> LDS (lds dest = wave-uniform base + lane*16) ------
__device__ __forceinline__ void ld16(unsigned char* ldsp, const unsigned char* gp) {
  __builtin_amdgcn_global_load_lds(
      (const __attribute__((address_space(1))) unsigned int*)gp,
      (__attribute__((address_space(3))) unsigned int*)ldsp, 16, 0, 0);
}

// ---- kernel 4: implicit GEMM, LDS-staged periods ---------------------------
// Block: 2 waves = rows i0, i0+1 (i0 = 2*rq). Period = 9 K-steps = 36 KB
// weights + 4 c-planes x 4 rows (i0..i0+3) of spline features (16 KB).
// Silu phase staged as a 10th "period" (36 KB weights + 4 rows x 4 KB, with
// XOR swizzle so fragment ds_reads are a permutation of contiguous 1 KB).
__global__ __launch_bounds__(128) void k_gemm(const unsigned char* __restrict__ ws,
                                              float* __restrict__ out) {
  __shared__ __align__(16) unsigned char wlds[36864];
  __shared__ __align__(16) unsigned char flds[16384 + 512];   // +pad for j>=62 overreads

  const int blk = blockIdx.x;            // b*31 + rq   (496 blocks)
  const int b = blk / 31, rq = blk - b * 31;
  const int i0 = rq * 2;
  const int tid = threadIdx.x;
  const int wave = tid >> 6, lane = tid & 63;
  const int q = lane >> 4, ln = lane & 15;
  const int i = i0 + wave;               // this wave's output row, always < 62

  auto stage = [&](int tn) {             // tn = 0..7 spline period, 8 = silu
    for (int u = wave; u < 52; u += 2) {
      if (u < 36) {                      // weights: steps 9tn..9tn+8, contiguous
        ld16(wlds + u * 1024,
             ws + WPACK_OFF + (size_t)tn * 36864 + (size_t)u * 1024 + lane * 16);
      } else if (tn < 8) {               // spline rows (c=4tn+cp, y=i0+r)
        int v = u - 36, cp = v >> 2, r = v & 3;
        ld16(flds + v * 1024,
             ws + FSPL_OFF +
                 ((size_t)((b * 32 + tn * 4 + cp) * 64 + (i0 + r))) * 1024 + lane * 16);
      } else {                           // silu rows, XOR-swizzled placement
        int v = u - 36, r = v >> 2, p4 = v & 3;
        ld16(flds + v * 1024,
             ws + FSILU_OFF + (size_t)(b * 64 + i0 + r) * 4096 +
                 (p4 * 16 + (lane >> 2)) * 64 + ((lane & 3) ^ ((lane >> 2) & 3)) * 16);
      }
    }
  };

  // per-lane spline fragment offsets within staged period (chunk = cp*4 + row)
  int foff[9];
#pragma unroll
  for (int sg = 0; sg < 9; ++sg) {
    int rid = 4 * sg + q;
    int ch = rid / 3, sub = rid - ch * 3;
    int cp = ch / 3, di = ch - cp * 3;
    foff[sg] = (cp * 4 + wave + di) * 1024 + (sub + ln) * 16;
  }

  v4f acc[4][4];
#pragma unroll
  for (int a = 0; a < 4; ++a)
#pragma unroll
    for (int c = 0; c < 4; ++c) acc[a][c] = (v4f){0.f, 0.f, 0.f, 0.f};

  stage(0);
  __syncthreads();

#pragma unroll 1
  for (int t = 0; t < 8; ++t) {
#pragma unroll
    for (int sg = 0; sg < 9; ++sg) {
      v8s wb[4], fb[4];
#pragma unroll
      for (int ot = 0; ot < 4; ++ot)
        wb[ot] = *(const v8s*)(wlds + sg * 4096 + ot * 1024 + lane * 16);
#pragma unroll
      for (int pt = 0; pt < 4; ++pt)
        fb[pt] = *(const v8s*)(flds + foff[sg] + pt * 256);
#pragma unroll
      for (int ot = 0; ot < 4; ++ot)
#pragma unroll
        for (int pt = 0; pt < 4; ++pt)
          acc[ot][pt] = __builtin_amdgcn_mfma_f32_16x16x32_bf16(
              wb[ot], fb[pt], acc[ot][pt], 0, 0, 0);
    }
    __syncthreads();                     // all reads of this period done
    stage(t + 1);                        // t+1 == 8 -> silu stage
    __syncthreads();                     // staged data visible (vmcnt drained)
  }

  // ---- silu phase (staged as period 8) -------------------------------------
#pragma unroll
  for (int e = 0; e < 9; ++e) {
    const int di = e / 3, dj = e % 3;
    v8s wb[4], fb[4];
#pragma unroll
    for (int ot = 0; ot < 4; ++ot)
      wb[ot] = *(const v8s*)(wlds + e * 4096 + ot * 1024 + lane * 16);
    const int xb = dj + ln;              // x = xb + pt*16; (x&3) == (xb&3)
    const int sbase = (wave + di) * 4096 + xb * 64 + ((q ^ (xb & 3)) * 16);
#pragma unroll
    for (int pt = 0; pt < 4; ++pt)
      fb[pt] = *(const v8s*)(flds + sbase + pt * 1024);
#pragma unroll
    for (int ot = 0; ot < 4; ++ot)
#pragma unroll
      for (int pt = 0; pt < 4; ++pt)
        acc[ot][pt] = __builtin_amdgcn_mfma_f32_16x16x32_bf16(
            wb[ot], fb[pt], acc[ot][pt], 0, 0, 0);
  }

  // ---- epilogue: C/D layout col(n=j)=lane&15, row(m=o)=q*4+reg -------------
#pragma unroll
  for (int ot = 0; ot < 4; ++ot)
#pragma unroll
    for (int pt = 0; pt < 4; ++pt) {
      const int j = pt * 16 + ln;
      if (j < 62) {
#pragma unroll
        for (int r = 0; r < 4; ++r) {
          const int o = ot * 16 + q * 4 + r;
          out[(((size_t)b * 64 + o) * 62 + i) * 62 + j] = acc[ot][pt][r];
        }
      }
    }
}

extern "C" void kernel_launch(void* const* d_in, const int* in_sizes, int n_in,
                              void* d_out, int out_size, void* d_ws, size_t ws_size,
                              hipStream_t stream) {
  const float* x  = (const float*)d_in[0];
  const float* bw = (const float*)d_in[1];
  const float* sw = (const float*)d_in[2];
  const float* sc = (const float*)d_in[3];
  unsigned char* ws = (unsigned char*)d_ws;
  float* out = (float*)d_out;

  hipLaunchKernelGGL(k_spline, dim3(8192), dim3(256), 0, stream, x, ws);
  hipLaunchKernelGGL(k_silu,   dim3(1024), dim3(256), 0, stream, x, ws);
  hipLaunchKernelGGL(k_wpack,  dim3(648),  dim3(256), 0, stream, bw, sw, sc, ws);
  hipLaunchKernelGGL(k_gemm,   dim3(496),  dim3(128), 0, stream, ws, out);
}

// Round 5
// 110.966 us; speedup vs baseline: 1.1592x; 1.1592x over previous
//
#include <hip/hip_runtime.h>

// ---------------------------------------------------------------------------
// KAN conv layer: out[b,o,i,j] = sum_{c,p} silu(patch)*bw[o,c,p]
//                              + sum_{c,p,g} Bspline_g(patch)*sw[o,c,p,g]*sc[o,c,p]
// B=16 CIN=32 COUT=64 H=W=64 K=3 -> Ho=Wo=62, P=9, G+k=8 bases
// bf16 MFMA implicit GEMM, K = 2592 = 81 steps of 32 (72 spline + 9 silu).
// R5: double-buffered LDS stages, 4 rows/block (4 waves, 256 thr), grid 256
//     (1 block/CU, no tail). stage(t+1) issued async into buf[(t+1)&1] BEFORE
//     computing period t from buf[t&1] -> staging hides under ~2300 cyc of
//     MFMA. Evidence: R1-R4 all ~45-51us at ~9% occupancy & 15% MfmaUtil
//     regardless of traffic -> operand-feed latency was the invariant, not BW.
// ---------------------------------------------------------------------------

typedef short v8s __attribute__((ext_vector_type(8)));
typedef float v4f __attribute__((ext_vector_type(4)));

#define FSPL_OFF   0u
#define FSILU_OFF  33554688u          // 33554432 (Fspl) + 256 pad
#define WPACK_OFF  37749248u          // FSILU_OFF + 4194304 (Fsil) + 256 pad

__device__ __forceinline__ unsigned short f2bf(float f) {
  unsigned int u = __float_as_uint(f);
  u += 0x7fffu + ((u >> 16) & 1u);          // round-to-nearest-even
  return (unsigned short)(u >> 16);
}

// ---- kernel 1: spline bases per input element -> Fspl[b][c][y][x][g8] ------
__global__ __launch_bounds__(256) void k_spline(const float* __restrict__ x,
                                                unsigned char* __restrict__ ws) {
  int pix = blockIdx.x * 256 + threadIdx.x;      // 2,097,152 elements
  float v = x[pix];
  float bb[11];
#pragma unroll
  for (int i = 0; i < 11; ++i) {
    float t0 = -2.2f + 0.4f * i;
    bb[i] = (v >= t0 && v < t0 + 0.4f) ? 1.0f : 0.0f;
  }
#pragma unroll
  for (int j = 1; j <= 3; ++j) {
    float rj = 1.0f / (0.4f * j);
#pragma unroll
    for (int i = 0; i + j < 11; ++i) {
      float ti = -2.2f + 0.4f * i;
      float lf = (v - ti) * rj;
      float rt = ((ti + 0.4f * (j + 1)) - v) * rj;
      bb[i] = lf * bb[i] + rt * bb[i + 1];
    }
  }
  uint4 o;
  o.x = (unsigned)f2bf(bb[0]) | ((unsigned)f2bf(bb[1]) << 16);
  o.y = (unsigned)f2bf(bb[2]) | ((unsigned)f2bf(bb[3]) << 16);
  o.z = (unsigned)f2bf(bb[4]) | ((unsigned)f2bf(bb[5]) << 16);
  o.w = (unsigned)f2bf(bb[6]) | ((unsigned)f2bf(bb[7]) << 16);
  *(uint4*)(ws + FSPL_OFF + (size_t)pix * 16) = o;
}

// ---- kernel 2: silu, transposed -> Fsil[b][y][x][c32] ----------------------
__global__ __launch_bounds__(256) void k_silu(const float* __restrict__ x,
                                              unsigned char* __restrict__ ws) {
  int bid = blockIdx.x;                  // b*64 + y
  int b = bid >> 6, y = bid & 63;
  int t = threadIdx.x;
  int xx = t & 63, cg = t >> 6;
  unsigned short h[8];
#pragma unroll
  for (int k = 0; k < 8; ++k) {
    int c = cg * 8 + k;
    float v = x[(((size_t)(b * 32 + c) * 64 + y) * 64) + xx];
    float s = v / (1.0f + __expf(-v));
    h[k] = f2bf(s);
  }
  uint4 o;
  o.x = (unsigned)h[0] | ((unsigned)h[1] << 16);
  o.y = (unsigned)h[2] | ((unsigned)h[3] << 16);
  o.z = (unsigned)h[4] | ((unsigned)h[5] << 16);
  o.w = (unsigned)h[6] | ((unsigned)h[7] << 16);
  *(uint4*)(ws + FSILU_OFF + (size_t)(b * 4096 + y * 64 + xx) * 64 + cg * 16) = o;
}

// ---- kernel 3: pack weights in MFMA A-fragment order -----------------------
__global__ __launch_bounds__(256) void k_wpack(const float* __restrict__ bw,
                                               const float* __restrict__ sw,
                                               const float* __restrict__ sc,
                                               unsigned char* __restrict__ ws) {
  int tid = blockIdx.x * 256 + threadIdx.x;
  if (tid >= 165888) return;             // 81*4*64*8
  int e = tid & 7, lane = (tid >> 3) & 63, ot = (tid >> 9) & 3, s = tid >> 11;
  int k = s * 32 + ((lane >> 4) << 3) + e;
  int o = (ot << 4) + (lane & 15);
  float val;
  if (k < 2304) {
    int chunk = k / 24, u = k - chunk * 24;
    int dj = u >> 3, g = u & 7;
    int c = chunk / 3, di = chunk - c * 3;
    int p = di * 3 + dj;
    val = sw[((size_t)(o * 32 + c) * 9 + p) * 8 + g] * sc[(size_t)(o * 32 + c) * 9 + p];
  } else {
    int k2 = k - 2304;
    int tp = k2 >> 5, cc = k2 & 31;
    val = bw[(size_t)(o * 32 + cc) * 9 + tp];
  }
  *(unsigned short*)(ws + WPACK_OFF + (size_t)tid * 2) = f2bf(val);
}

// ---- async 16B global -> LDS (lds dest = wave-uniform base + lane*16) ------
__device__ __forceinline__ void ld16(unsigned char* ldsp, const unsigned char* gp) {
  __builtin_amdgcn_global_load_lds(
      (const __attribute__((address_space(1))) unsigned int*)gp,
      (__attribute__((address_space(3))) unsigned int*)ldsp, 16, 0, 0);
}

// ---- kernel 4: implicit GEMM, double-buffered LDS-staged periods -----------
// Block: 4 waves = rows i0..i0+3 (i0 = 16*(blk&15)... see below). Period =
// 9 K-steps: 36 KB weights + 4 c-planes x 6 rows (i0..i0+5) features (24 KB).
// Silu staged as period 8 (36 KB weights + 6 rows x 4 KB, XOR-swizzled).
__global__ __launch_bounds__(256) void k_gemm(const unsigned char* __restrict__ ws,
                                              float* __restrict__ out) {
  __shared__ __align__(16) unsigned char wlds[2][36864];
  __shared__ __align__(16) unsigned char flds[2][25088];   // 24 KB + overread pad

  const int blk = blockIdx.x;            // b*16 + ig   (256 blocks, 1/CU)
  const int b = blk >> 4, ig = blk & 15;
  const int i0 = ig * 4;
  const int tid = threadIdx.x;
  const int wave = tid >> 6, lane = tid & 63;
  const int q = lane >> 4, ln = lane & 15;
  const int i = i0 + wave;               // this wave's output row (62,63 masked)

  auto stage = [&](int tn, int bi) {     // tn = 0..7 spline period, 8 = silu
#pragma unroll
    for (int it = 0; it < 15; ++it) {    // 60 chunks of 1 KB over 4 waves
      const int u = wave + it * 4;
      if (it < 9) {                      // u<36 always: weight steps 9tn..9tn+8
        ld16(&wlds[bi][u * 1024],
             ws + WPACK_OFF + (size_t)tn * 36864 + (size_t)u * 1024 + lane * 16);
      } else if (tn < 8) {               // spline rows (c=4tn+cp, y=i0+r)
        const int v = u - 36;            // 0..23
        const int cp = v / 6, r = v - cp * 6;
        ld16(&flds[bi][v * 1024],
             ws + FSPL_OFF +
                 ((size_t)((b * 32 + tn * 4 + cp) * 64 + i0 + r)) * 1024 + lane * 16);
      } else {                           // silu rows, XOR-swizzled placement
        const int v = u - 36;
        const int r = v >> 2, p4 = v & 3;
        ld16(&flds[bi][v * 1024],
             ws + FSILU_OFF + (size_t)(b * 64 + i0 + r) * 4096 +
                 (p4 * 16 + (lane >> 2)) * 64 + ((lane & 3) ^ ((lane >> 2) & 3)) * 16);
      }
    }
  };

  // per-lane spline fragment offsets within a staged period
  int foff[9];
#pragma unroll
  for (int sg = 0; sg < 9; ++sg) {
    int rid = 4 * sg + q;
    int ch = rid / 3, sub = rid - ch * 3;
    int cp = ch / 3, di = ch - cp * 3;
    foff[sg] = (cp * 6 + wave + di) * 1024 + (sub + ln) * 16;
  }

  v4f acc[4][4];
#pragma unroll
  for (int a = 0; a < 4; ++a)
#pragma unroll
    for (int c = 0; c < 4; ++c) acc[a][c] = (v4f){0.f, 0.f, 0.f, 0.f};

  stage(0, 0);
  __syncthreads();

#pragma unroll 1
  for (int t = 0; t < 8; ++t) {
    stage(t + 1, (t + 1) & 1);           // async prefetch into other buffer
    const unsigned char* wb_base = wlds[t & 1];
    const unsigned char* fb_base = flds[t & 1];
#pragma unroll
    for (int sg = 0; sg < 9; ++sg) {
      v8s wb[4], fb[4];
#pragma unroll
      for (int ot = 0; ot < 4; ++ot)
        wb[ot] = *(const v8s*)(wb_base + sg * 4096 + ot * 1024 + lane * 16);
#pragma unroll
      for (int pt = 0; pt < 4; ++pt)
        fb[pt] = *(const v8s*)(fb_base + foff[sg] + pt * 256);
#pragma unroll
      for (int ot = 0; ot < 4; ++ot)
#pragma unroll
        for (int pt = 0; pt < 4; ++pt)
          acc[ot][pt] = __builtin_amdgcn_mfma_f32_16x16x32_bf16(
              wb[ot], fb[pt], acc[ot][pt], 0, 0, 0);
    }
    __syncthreads();                     // buf[t] reads done; stage(t+1) landed
  }

  // ---- silu phase (staged as period 8, in buffer 0) ------------------------
#pragma unroll
  for (int e = 0; e < 9; ++e) {
    const int di = e / 3, dj = e % 3;
    v8s wb[4], fb[4];
#pragma unroll
    for (int ot = 0; ot < 4; ++ot)
      wb[ot] = *(const v8s*)(&wlds[0][0] + e * 4096 + ot * 1024 + lane * 16);
    const int xb = dj + ln;              // x = xb + pt*16; (x&3) == (xb&3)
    const int sbase = (wave + di) * 4096 + xb * 64 + ((q ^ (xb & 3)) * 16);
#pragma unroll
    for (int pt = 0; pt < 4; ++pt)
      fb[pt] = *(const v8s*)(&flds[0][0] + sbase + pt * 1024);
#pragma unroll
    for (int ot = 0; ot < 4; ++ot)
#pragma unroll
      for (int pt = 0; pt < 4; ++pt)
        acc[ot][pt] = __builtin_amdgcn_mfma_f32_16x16x32_bf16(
            wb[ot], fb[pt], acc[ot][pt], 0, 0, 0);
  }

  // ---- epilogue: C/D layout col(n=j)=lane&15, row(m=o)=q*4+reg -------------
  if (i < 62) {
#pragma unroll
    for (int ot = 0; ot < 4; ++ot)
#pragma unroll
      for (int pt = 0; pt < 4; ++pt) {
        const int j = pt * 16 + ln;
        if (j < 62) {
#pragma unroll
          for (int r = 0; r < 4; ++r) {
            const int o = ot * 16 + q * 4 + r;
            out[(((size_t)b * 64 + o) * 62 + i) * 62 + j] = acc[ot][pt][r];
          }
        }
      }
  }
}

extern "C" void kernel_launch(void* const* d_in, const int* in_sizes, int n_in,
                              void* d_out, int out_size, void* d_ws, size_t ws_size,
                              hipStream_t stream) {
  const float* x  = (const float*)d_in[0];
  const float* bw = (const float*)d_in[1];
  const float* sw = (const float*)d_in[2];
  const float* sc = (const float*)d_in[3];
  unsigned char* ws = (unsigned char*)d_ws;
  float* out = (float*)d_out;

  hipLaunchKernelGGL(k_spline, dim3(8192), dim3(256), 0, stream, x, ws);
  hipLaunchKernelGGL(k_silu,   dim3(1024), dim3(256), 0, stream, x, ws);
  hipLaunchKernelGGL(k_wpack,  dim3(648),  dim3(256), 0, stream, bw, sw, sc, ws);
  hipLaunchKernelGGL(k_gemm,   dim3(256),  dim3(256), 0, stream, ws, out);
}

// Round 6
// 105.599 us; speedup vs baseline: 1.2181x; 1.0508x over previous
//
#include <hip/hip_runtime.h>

// ---------------------------------------------------------------------------
// KAN conv layer: out[b,o,i,j] = sum_{c,p} silu(patch)*bw[o,c,p]
//                              + sum_{c,p,g} Bspline_g(patch)*sw[o,c,p,g]*sc[o,c,p]
// B=16 CIN=32 COUT=64 H=W=64 K=3 -> Ho=Wo=62, P=9, G+k=8 bases
// bf16 MFMA implicit GEMM, K = 2592 = 81 steps of 32 (72 spline + 9 silu).
// R5: double-buffered LDS staging, 1 block/CU -> k_gemm ~36us. Invariant
//     across R1-R5: exactly 1 MFMA wave per SIMD -> pipe gaps (ds_read,
//     waitcnt, barrier) have no co-resident wave to fill them (m114).
// R6: 8 waves/block = 2 waves/SIMD. Wave = (row r, o-half oh): 2 ot x 4 pt
//     = 8 MFMA/step, acc[2][4]. Two waves interleave on each SIMD. LDS
//     traffic/step 32->48 KB (features read by both o-halves) -> LDS-pipe
//     floor ~14.5us; expect 16-20us.
// ---------------------------------------------------------------------------

typedef short v8s __attribute__((ext_vector_type(8)));
typedef float v4f __attribute__((ext_vector_type(4)));

#define FSPL_OFF   0u
#define FSILU_OFF  33554688u          // 33554432 (Fspl) + 256 pad
#define WPACK_OFF  37749248u          // FSILU_OFF + 4194304 (Fsil) + 256 pad

__device__ __forceinline__ unsigned short f2bf(float f) {
  unsigned int u = __float_as_uint(f);
  u += 0x7fffu + ((u >> 16) & 1u);          // round-to-nearest-even
  return (unsigned short)(u >> 16);
}

// ---- kernel 1: spline bases per input element -> Fspl[b][c][y][x][g8] ------
__global__ __launch_bounds__(256) void k_spline(const float* __restrict__ x,
                                                unsigned char* __restrict__ ws) {
  int pix = blockIdx.x * 256 + threadIdx.x;      // 2,097,152 elements
  float v = x[pix];
  float bb[11];
#pragma unroll
  for (int i = 0; i < 11; ++i) {
    float t0 = -2.2f + 0.4f * i;
    bb[i] = (v >= t0 && v < t0 + 0.4f) ? 1.0f : 0.0f;
  }
#pragma unroll
  for (int j = 1; j <= 3; ++j) {
    float rj = 1.0f / (0.4f * j);
#pragma unroll
    for (int i = 0; i + j < 11; ++i) {
      float ti = -2.2f + 0.4f * i;
      float lf = (v - ti) * rj;
      float rt = ((ti + 0.4f * (j + 1)) - v) * rj;
      bb[i] = lf * bb[i] + rt * bb[i + 1];
    }
  }
  uint4 o;
  o.x = (unsigned)f2bf(bb[0]) | ((unsigned)f2bf(bb[1]) << 16);
  o.y = (unsigned)f2bf(bb[2]) | ((unsigned)f2bf(bb[3]) << 16);
  o.z = (unsigned)f2bf(bb[4]) | ((unsigned)f2bf(bb[5]) << 16);
  o.w = (unsigned)f2bf(bb[6]) | ((unsigned)f2bf(bb[7]) << 16);
  *(uint4*)(ws + FSPL_OFF + (size_t)pix * 16) = o;
}

// ---- kernel 2: silu, transposed -> Fsil[b][y][x][c32] ----------------------
__global__ __launch_bounds__(256) void k_silu(const float* __restrict__ x,
                                              unsigned char* __restrict__ ws) {
  int bid = blockIdx.x;                  // b*64 + y
  int b = bid >> 6, y = bid & 63;
  int t = threadIdx.x;
  int xx = t & 63, cg = t >> 6;
  unsigned short h[8];
#pragma unroll
  for (int k = 0; k < 8; ++k) {
    int c = cg * 8 + k;
    float v = x[(((size_t)(b * 32 + c) * 64 + y) * 64) + xx];
    float s = v / (1.0f + __expf(-v));
    h[k] = f2bf(s);
  }
  uint4 o;
  o.x = (unsigned)h[0] | ((unsigned)h[1] << 16);
  o.y = (unsigned)h[2] | ((unsigned)h[3] << 16);
  o.z = (unsigned)h[4] | ((unsigned)h[5] << 16);
  o.w = (unsigned)h[6] | ((unsigned)h[7] << 16);
  *(uint4*)(ws + FSILU_OFF + (size_t)(b * 4096 + y * 64 + xx) * 64 + cg * 16) = o;
}

// ---- kernel 3: pack weights in MFMA A-fragment order -----------------------
__global__ __launch_bounds__(256) void k_wpack(const float* __restrict__ bw,
                                               const float* __restrict__ sw,
                                               const float* __restrict__ sc,
                                               unsigned char* __restrict__ ws) {
  int tid = blockIdx.x * 256 + threadIdx.x;
  if (tid >= 165888) return;             // 81*4*64*8
  int e = tid & 7, lane = (tid >> 3) & 63, ot = (tid >> 9) & 3, s = tid >> 11;
  int k = s * 32 + ((lane >> 4) << 3) + e;
  int o = (ot << 4) + (lane & 15);
  float val;
  if (k < 2304) {
    int chunk = k / 24, u = k - chunk * 24;
    int dj = u >> 3, g = u & 7;
    int c = chunk / 3, di = chunk - c * 3;
    int p = di * 3 + dj;
    val = sw[((size_t)(o * 32 + c) * 9 + p) * 8 + g] * sc[(size_t)(o * 32 + c) * 9 + p];
  } else {
    int k2 = k - 2304;
    int tp = k2 >> 5, cc = k2 & 31;
    val = bw[(size_t)(o * 32 + cc) * 9 + tp];
  }
  *(unsigned short*)(ws + WPACK_OFF + (size_t)tid * 2) = f2bf(val);
}

// ---- async 16B global -> LDS (lds dest = wave-uniform base + lane*16) ------
__device__ __forceinline__ void ld16(unsigned char* ldsp, const unsigned char* gp) {
  __builtin_amdgcn_global_load_lds(
      (const __attribute__((address_space(1))) unsigned int*)gp,
      (__attribute__((address_space(3))) unsigned int*)ldsp, 16, 0, 0);
}

// ---- kernel 4: implicit GEMM, dbuf LDS stages, 2 MFMA waves per SIMD -------
// Block: 8 waves. Wave = (row r = w>>1 of 4, o-half oh = w&1). Each wave:
// 2 ot x 4 pt MFMA tiles per K-step. Period = 9 steps: 36 KB weights +
// 4 c-planes x 6 rows features (24 KB); silu staged as period 8 (XOR-swizzle).
__global__ __launch_bounds__(512) void k_gemm(const unsigned char* __restrict__ ws,
                                              float* __restrict__ out) {
  __shared__ __align__(16) unsigned char wlds[2][36864];
  __shared__ __align__(16) unsigned char flds[2][25088];   // 24 KB + overread pad

  const int blk = blockIdx.x;            // b*16 + ig   (256 blocks, 1/CU)
  const int b = blk >> 4, ig = blk & 15;
  const int i0 = ig * 4;
  const int tid = threadIdx.x;
  const int wave = tid >> 6, lane = tid & 63;
  const int q = lane >> 4, ln = lane & 15;
  const int r = wave >> 1;               // row 0..3 within block
  const int oh = wave & 1;               // o-half: ot = oh*2 + tt
  const int i = i0 + r;                  // output row (62,63 masked at store)

  auto stage = [&](int tn, int bi) {     // tn = 0..7 spline period, 8 = silu
#pragma unroll
    for (int it = 0; it < 8; ++it) {     // 60 chunks of 1 KB over 8 waves
      const int u = wave + it * 8;
      if (u < 36) {                      // weight steps 9tn..9tn+8, contiguous
        ld16(&wlds[bi][u * 1024],
             ws + WPACK_OFF + (size_t)tn * 36864 + (size_t)u * 1024 + lane * 16);
      } else if (u < 60) {
        const int v = u - 36;            // 0..23 feature chunks
        if (tn < 8) {                    // spline rows (c=4tn+cp, y=i0+rr)
          const int cp = v / 6, rr = v - cp * 6;
          ld16(&flds[bi][v * 1024],
               ws + FSPL_OFF +
                   ((size_t)((b * 32 + tn * 4 + cp) * 64 + i0 + rr)) * 1024 + lane * 16);
        } else {                         // silu rows, XOR-swizzled placement
          const int rr = v >> 2, p4 = v & 3;
          ld16(&flds[bi][v * 1024],
               ws + FSILU_OFF + (size_t)(b * 64 + i0 + rr) * 4096 +
                   (p4 * 16 + (lane >> 2)) * 64 + ((lane & 3) ^ ((lane >> 2) & 3)) * 16);
        }
      }
    }
  };

  // per-lane spline fragment offsets within a staged period (row = r)
  int foff[9];
#pragma unroll
  for (int sg = 0; sg < 9; ++sg) {
    int rid = 4 * sg + q;
    int ch = rid / 3, sub = rid - ch * 3;
    int cp = ch / 3, di = ch - cp * 3;
    foff[sg] = (cp * 6 + r + di) * 1024 + (sub + ln) * 16;
  }

  v4f acc[2][4];
#pragma unroll
  for (int a = 0; a < 2; ++a)
#pragma unroll
    for (int c = 0; c < 4; ++c) acc[a][c] = (v4f){0.f, 0.f, 0.f, 0.f};

  stage(0, 0);
  __syncthreads();

#pragma unroll 1
  for (int t = 0; t < 8; ++t) {
    stage(t + 1, (t + 1) & 1);           // async prefetch into other buffer
    const unsigned char* wb_base = wlds[t & 1];
    const unsigned char* fb_base = flds[t & 1];
#pragma unroll
    for (int sg = 0; sg < 9; ++sg) {
      v8s wb[2], fb[4];
#pragma unroll
      for (int tt = 0; tt < 2; ++tt)
        wb[tt] = *(const v8s*)(wb_base + sg * 4096 + (oh * 2 + tt) * 1024 + lane * 16);
#pragma unroll
      for (int pt = 0; pt < 4; ++pt)
        fb[pt] = *(const v8s*)(fb_base + foff[sg] + pt * 256);
#pragma unroll
      for (int tt = 0; tt < 2; ++tt)
#pragma unroll
        for (int pt = 0; pt < 4; ++pt)
          acc[tt][pt] = __builtin_amdgcn_mfma_f32_16x16x32_bf16(
              wb[tt], fb[pt], acc[tt][pt], 0, 0, 0);
    }
    __syncthreads();                     // buf[t] reads done; stage(t+1) landed
  }

  // ---- silu phase (staged as period 8, in buffer 0) ------------------------
#pragma unroll
  for (int e = 0; e < 9; ++e) {
    const int di = e / 3, dj = e % 3;
    v8s wb[2], fb[4];
#pragma unroll
    for (int tt = 0; tt < 2; ++tt)
      wb[tt] = *(const v8s*)(&wlds[0][0] + e * 4096 + (oh * 2 + tt) * 1024 + lane * 16);
    const int xb = dj + ln;              // x = xb + pt*16; (x&3) == (xb&3)
    const int sbase = (r + di) * 4096 + xb * 64 + ((q ^ (xb & 3)) * 16);
#pragma unroll
    for (int pt = 0; pt < 4; ++pt)
      fb[pt] = *(const v8s*)(&flds[0][0] + sbase + pt * 1024);
#pragma unroll
    for (int tt = 0; tt < 2; ++tt)
#pragma unroll
      for (int pt = 0; pt < 4; ++pt)
        acc[tt][pt] = __builtin_amdgcn_mfma_f32_16x16x32_bf16(
            wb[tt], fb[pt], acc[tt][pt], 0, 0, 0);
  }

  // ---- epilogue: C/D layout col(n=j)=lane&15, row(m=o)=q*4+reg -------------
  if (i < 62) {
#pragma unroll
    for (int tt = 0; tt < 2; ++tt)
#pragma unroll
      for (int pt = 0; pt < 4; ++pt) {
        const int j = pt * 16 + ln;
        if (j < 62) {
#pragma unroll
          for (int rr = 0; rr < 4; ++rr) {
            const int o = (oh * 2 + tt) * 16 + q * 4 + rr;
            out[(((size_t)b * 64 + o) * 62 + i) * 62 + j] = acc[tt][pt][rr];
          }
        }
      }
  }
}

extern "C" void kernel_launch(void* const* d_in, const int* in_sizes, int n_in,
                              void* d_out, int out_size, void* d_ws, size_t ws_size,
                              hipStream_t stream) {
  const float* x  = (const float*)d_in[0];
  const float* bw = (const float*)d_in[1];
  const float* sw = (const float*)d_in[2];
  const float* sc = (const float*)d_in[3];
  unsigned char* ws = (unsigned char*)d_ws;
  float* out = (float*)d_out;

  hipLaunchKernelGGL(k_spline, dim3(8192), dim3(256), 0, stream, x, ws);
  hipLaunchKernelGGL(k_silu,   dim3(1024), dim3(256), 0, stream, x, ws);
  hipLaunchKernelGGL(k_wpack,  dim3(648),  dim3(256), 0, stream, bw, sw, sc, ws);
  hipLaunchKernelGGL(k_gemm,   dim3(256),  dim3(512), 0, stream, ws, out);
}